// Round 1
// baseline (100.581 us; speedup 1.0000x reference)
//
#include <hip/hip_runtime.h>
#include <float.h>
#include <math.h>
#include <stdint.h>

// Problem constants (fixed by reference)
#define VOCAB   128000
#define HIST    2048
#define TOPK    15
#define NB_TOPK 64
#define CHUNK   (VOCAB / NB_TOPK)   // 2000
#define NCAND   (NB_TOPK * TOPK)    // 960
#define NB_ARG  128
#define REP_PEN 1.35f

struct Ws {
  unsigned long long best;     // packed argmax result
  unsigned int cnt_topk;       // last-block counter for topk kernel
  unsigned int cnt_arg;        // last-block counter for argmax kernel
  float pivot;                 // 15th largest penalized logit
  float pad;
  float cand[NCAND];           // per-block top-15 candidates
};

// monotonic float->uint mapping (order-preserving, total)
__device__ __forceinline__ unsigned int f2ord(float f) {
  unsigned int b = __float_as_uint(f);
  return b ^ ((b & 0x80000000u) ? 0xFFFFFFFFu : 0x80000000u);
}
__device__ __forceinline__ float ord2f(unsigned int u) {
  unsigned int b = (u & 0x80000000u) ? (u ^ 0x80000000u) : (u ^ 0xFFFFFFFFu);
  return __uint_as_float(b);
}

// ---------------------------------------------------------------------------
// K1: repetition penalty (in place on logits), y copy to out[1..2048], ws init.
// Single block so the gather-all / barrier / scatter-all ordering is exact:
// duplicate tokens in y all read the ORIGINAL value and write the same score.
// ---------------------------------------------------------------------------
__global__ void penalty_init_kernel(float* __restrict__ logits,
                                    const int* __restrict__ y,
                                    int* __restrict__ out,
                                    Ws* __restrict__ ws) {
  int tid = threadIdx.x;           // 1024 threads, 2 tokens each
  int t0 = y[tid];
  int t1 = y[tid + 1024];
  float v0 = logits[t0];
  float v1 = logits[t1];
  out[1 + tid] = t0;               // y_new[0..2047] = y
  out[1 + 1024 + tid] = t1;
  if (tid == 0) {
    ws->best = 0ull;
    ws->cnt_topk = 0u;
    ws->cnt_arg = 0u;
  }
  __syncthreads();                 // all reads of originals complete
  logits[t0] = (v0 < 0.0f) ? v0 * REP_PEN : v0 / REP_PEN;
  logits[t1] = (v1 < 0.0f) ? v1 * REP_PEN : v1 / REP_PEN;
}

// ---------------------------------------------------------------------------
// Shared helper: extract the top-15 values (descending, duplicates counted)
// from LDS array sv[0..n) with 256 threads. Optionally streams them to
// `store` (global). Returns the 15th value (valid on tid 0 only).
// ---------------------------------------------------------------------------
__device__ float extract15(float* sv, int n, unsigned long long* rw,
                           float* store) {
  int tid = threadIdx.x;
  float last = 0.0f;
  for (int it = 0; it < TOPK; ++it) {
    unsigned long long best = 0ull;  // any finite float packs > 0
    for (int i = tid; i < n; i += 256) {
      unsigned long long p =
          ((unsigned long long)f2ord(sv[i]) << 32) | (unsigned int)i;
      if (p > best) best = p;
    }
#pragma unroll
    for (int off = 32; off > 0; off >>= 1) {
      unsigned long long o = __shfl_down(best, off, 64);
      if (o > best) best = o;
    }
    if ((tid & 63) == 0) rw[tid >> 6] = best;
    __syncthreads();
    if (tid == 0) {
      unsigned long long m = rw[0];
      if (rw[1] > m) m = rw[1];
      if (rw[2] > m) m = rw[2];
      if (rw[3] > m) m = rw[3];
      int idx = (int)(unsigned int)(m & 0xFFFFFFFFull);
      float v = ord2f((unsigned int)(m >> 32));
      if (store) store[it] = v;
      sv[idx] = -FLT_MAX;          // remove this occurrence
      last = v;
    }
    __syncthreads();
  }
  return last;  // meaningful on tid 0 only
}

// ---------------------------------------------------------------------------
// K2: exact global 15th-largest (pivot). Per-block top-15 over a 2000-elem
// chunk staged in LDS; last-done block merges the 960 candidates.
// ---------------------------------------------------------------------------
__global__ __launch_bounds__(256) void topk_pivot_kernel(
    const float* __restrict__ logits, Ws* __restrict__ ws) {
  __shared__ float sv[CHUNK];
  __shared__ unsigned long long rw[4];
  __shared__ int last_flag;
  int tid = threadIdx.x;
  int b = blockIdx.x;
  const float* src = logits + b * CHUNK;
  for (int i = tid; i < CHUNK; i += 256) sv[i] = src[i];
  __syncthreads();
  extract15(sv, CHUNK, rw, ws->cand + b * TOPK);
  if (tid == 0) {
    __threadfence();               // publish candidate stores
    unsigned int prev = atomicAdd(&ws->cnt_topk, 1u);
    last_flag = (prev == NB_TOPK - 1) ? 1 : 0;
  }
  __syncthreads();
  if (!last_flag) return;
  __threadfence();                 // acquire: other blocks' candidates
  for (int i = tid; i < NCAND; i += 256) sv[i] = ws->cand[i];
  __syncthreads();
  float pivot = extract15(sv, NCAND, rw, nullptr);
  if (tid == 0) ws->pivot = pivot;
}

// ---------------------------------------------------------------------------
// K3: r_i = masked ? +0 : exp(v - pivot)/noise_i  (argmax-equivalent to
// softmax(masked logits)/noise, positive scale invariance). Global argmax
// with first-index tie-break via packed (ord(r)<<32)|~i and atomicMax.
// Last-done block decodes and writes out[0], out[2049].
// ---------------------------------------------------------------------------
__global__ __launch_bounds__(256) void sample_kernel(
    const float* __restrict__ logits, const float* __restrict__ noise,
    int* __restrict__ out, Ws* __restrict__ ws) {
  int tid = threadIdx.x;
  float pivot = ws->pivot;
  unsigned long long best = 0ull;
  int stride = gridDim.x * 256;
  for (int i = blockIdx.x * 256 + tid; i < VOCAB; i += stride) {
    float v = logits[i];
    float r = 0.0f;                          // masked -> exactly +0
    if (v >= pivot) r = expf(v - pivot) / noise[i];
    unsigned long long p = ((unsigned long long)f2ord(r) << 32) |
                           (unsigned int)(~(unsigned int)i);
    if (p > best) best = p;
  }
#pragma unroll
  for (int off = 32; off > 0; off >>= 1) {
    unsigned long long o = __shfl_down(best, off, 64);
    if (o > best) best = o;
  }
  if ((tid & 63) == 0) atomicMax(&ws->best, best);
  __syncthreads();
  if (tid == 0) {
    unsigned int prev = atomicAdd(&ws->cnt_arg, 1u);
    if (prev == (unsigned int)gridDim.x - 1) {
      unsigned long long w = atomicMax(&ws->best, 0ull);  // coherent read
      int idx = (int)(~(unsigned int)(w & 0xFFFFFFFFull));
      out[0] = idx;          // samples
      out[1 + HIST] = idx;   // y_new[2048]
    }
  }
}

extern "C" void kernel_launch(void* const* d_in, const int* in_sizes, int n_in,
                              void* d_out, int out_size, void* d_ws,
                              size_t ws_size, hipStream_t stream) {
  (void)in_sizes; (void)n_in; (void)out_size; (void)ws_size;
  float* logits = (float*)d_in[0];       // modified in place; harness restores
  const int* y = (const int*)d_in[1];
  const float* noise = (const float*)d_in[2];
  int* out = (int*)d_out;
  Ws* ws = (Ws*)d_ws;
  hipLaunchKernelGGL(penalty_init_kernel, dim3(1), dim3(1024), 0, stream,
                     logits, y, out, ws);
  hipLaunchKernelGGL(topk_pivot_kernel, dim3(NB_TOPK), dim3(256), 0, stream,
                     logits, ws);
  hipLaunchKernelGGL(sample_kernel, dim3(NB_ARG), dim3(256), 0, stream,
                     logits, noise, out, ws);
}